// Round 9
// baseline (95.311 us; speedup 1.0000x reference)
//
#include <hip/hip_runtime.h>

// Chamfer loss: x,y (16, 4096, 3) fp32 -> scalar.
//
// d(x,y) = ||x||^2 + (||y||^2 - 2 x.y); min over y needs only
//   t = fma(-x0,2y0, fma(-x1,2y1, fma(-x2,2y2, ||y||^2))),  d = ||x||^2 + t
//
// Round-9: remove the DS pipe from the hot loop. Evidence: R2/R7/R8 all
// ~neutral at ~85 us end-to-end despite instruction-count and pipelining
// changes; the invariant across them is the per-y ds_read_b128 broadcast +
// lgkmcnt wait. R1's direct measurement (VALUBusy 55% at 2 waves/SIMD with
// compute that should cover DS latency) already showed the DS-wait path
// costs ~2.5x the pipe model. New structure:
//  - each lane loads+packs ONE y-point -> a 64-y tile lives in 4 VGPRs/lane;
//  - hot loop broadcasts y components via v_readlane (SGPR operand feeds
//    v_fma directly; k is an unroll-time constant);
//  - zero LDS, zero barriers, zero lgkm waits in the hot loop.
//  ~4.1 instr/pair -> ~14 us lane-op floor for 268M pairs.
// Frame unchanged from proven R2: XPT=8, YT=128 (2 tiles of 64), NYC=32,
// grid 1024, __launch_bounds__(256,4); out zeroed by part block 0.

__device__ __forceinline__ float rlane(float v, int k) {
    return __int_as_float(__builtin_amdgcn_readlane(__float_as_int(v), k));
}

constexpr int NPTS   = 4096;
constexpr int NBATCH = 16;
constexpr int BLOCK  = 256;
constexpr int XPT    = 8;                    // x-points per thread
constexpr int XCHUNK = BLOCK * XPT;          // 2048
constexpr int NXC    = NPTS / XCHUNK;        // 2
constexpr int NYC    = 32;                   // y-chunks
constexpr int YT     = NPTS / NYC;           // 128 y per block = 2 tiles of 64

// ---------------- pass 1: partial mins, readlane-broadcast hot loop --------

__global__ __launch_bounds__(BLOCK, 4) void chamfer_part_kernel(
    const float* __restrict__ x, const float* __restrict__ y,
    float* __restrict__ ws, float* __restrict__ out)
{
    if (blockIdx.x == 0 && threadIdx.x == 0) out[0] = 0.0f;

    const int b      = blockIdx.x / (NXC * NYC);
    const int xchunk = (blockIdx.x / NYC) % NXC;
    const int ychunk = blockIdx.x % NYC;
    const int lane   = threadIdx.x & 63;

    // This thread's 8 consecutive x-points (24 floats = 6 float4).
    const int xbase = xchunk * XCHUNK + threadIdx.x * XPT;
    const float4* xp4 = (const float4*)(x + ((size_t)b * NPTS + xbase) * 3);
    const float4 a0 = xp4[0], a1 = xp4[1], a2 = xp4[2];
    const float4 a3 = xp4[3], a4 = xp4[4], a5 = xp4[5];
    const float xa[XPT][3] = {
        {a0.x, a0.y, a0.z}, {a0.w, a1.x, a1.y},
        {a1.z, a1.w, a2.x}, {a2.y, a2.z, a2.w},
        {a3.x, a3.y, a3.z}, {a3.w, a4.x, a4.y},
        {a4.z, a4.w, a5.x}, {a5.y, a5.z, a5.w}};

    float m[XPT];
    #pragma unroll
    for (int i = 0; i < XPT; ++i) m[i] = 3.4e38f;

    const float* ybase = y + ((size_t)b * NPTS + ychunk * YT) * 3;

    #pragma unroll 1                         // keep I-cache footprint ~17 KB
    for (int tt = 0; tt < YT / 64; ++tt) {
        // Each lane packs its own y-point of this 64-y tile into 4 VGPRs.
        const float* yp = ybase + (tt * 64 + lane) * 3;
        const float y0 = yp[0], y1 = yp[1], y2 = yp[2];
        const float p0 = 2.0f * y0;
        const float p1 = 2.0f * y1;
        const float p2 = 2.0f * y2;
        const float pn = fmaf(y2, y2, fmaf(y1, y1, y0 * y0));

        #pragma unroll
        for (int k = 0; k < 64; k += 2) {
            const float q0 = rlane(p0, k),     q1 = rlane(p1, k);
            const float q2 = rlane(p2, k),     qn = rlane(pn, k);
            const float r0 = rlane(p0, k + 1), r1 = rlane(p1, k + 1);
            const float r2 = rlane(p2, k + 1), rn = rlane(pn, k + 1);
            #pragma unroll
            for (int i = 0; i < XPT; ++i) {
                const float t0 = fmaf(-xa[i][0], q0,
                                 fmaf(-xa[i][1], q1,
                                 fmaf(-xa[i][2], q2, qn)));
                const float t1 = fmaf(-xa[i][0], r0,
                                 fmaf(-xa[i][1], r1,
                                 fmaf(-xa[i][2], r2, rn)));
                m[i] = fminf(fminf(t0, t1), m[i]);   // -> v_min3_f32
            }
        }
    }

    // d = max(||x||^2 + min_t, 0), stored ws[b][ychunk][xpoint] coalesced.
    float* wp = ws + ((size_t)b * NYC + ychunk) * NPTS + xbase;
    #pragma unroll
    for (int i = 0; i < XPT; i += 4) {
        float4 o;
        float* oc = (float*)&o;
        #pragma unroll
        for (int k = 0; k < 4; ++k) {
            const int p = i + k;
            const float x2 = fmaf(xa[p][2], xa[p][2],
                             fmaf(xa[p][1], xa[p][1],
                                  xa[p][0] * xa[p][0]));
            oc[k] = fmaxf(x2 + m[p], 0.0f);
        }
        ((float4*)wp)[i / 4] = o;
    }
}

// ---------------- pass 2: min over ychunks, then sum -----------------------

__global__ __launch_bounds__(BLOCK) void chamfer_reduce_kernel(
    const float* __restrict__ ws, float* __restrict__ out)
{
    __shared__ float swsum[BLOCK / 64];
    const int idx = blockIdx.x * BLOCK + threadIdx.x;   // one x-point each
    const int b   = idx / NPTS;
    const int xp  = idx % NPTS;

    const float* p = ws + (size_t)b * NYC * NPTS + xp;
    float mn = 3.4e38f;
    #pragma unroll 8
    for (int yc = 0; yc < NYC; ++yc)
        mn = fminf(mn, p[(size_t)yc * NPTS]);

    float s = mn;
    for (int off = 32; off > 0; off >>= 1)
        s += __shfl_down(s, off, 64);
    const int wave = threadIdx.x >> 6;
    if ((threadIdx.x & 63) == 0) swsum[wave] = s;
    __syncthreads();
    if (threadIdx.x == 0) {
        float t = 0.f;
        #pragma unroll
        for (int w = 0; w < BLOCK / 64; ++w) t += swsum[w];
        atomicAdd(out, t * (1.0f / NPTS));
    }
}

// ---------------- fallback: atomic path (tiny ws) --------------------------

__global__ __launch_bounds__(BLOCK) void chamfer_min_atomic_kernel(
    const float* __restrict__ x, const float* __restrict__ y,
    unsigned int* __restrict__ ws_min)
{
    constexpr int YTILE = 256;
    constexpr int FNYC  = NPTS / YTILE;
    __shared__ float4 sy[YTILE];

    const int b      = blockIdx.x / (NXC * FNYC);
    const int xchunk = (blockIdx.x / FNYC) % NXC;
    const int ychunk = blockIdx.x % FNYC;

    {
        const float* yp = y + ((size_t)b * NPTS + ychunk * YTILE + threadIdx.x) * 3;
        const float y0 = yp[0], y1 = yp[1], y2 = yp[2];
        sy[threadIdx.x] = make_float4(2.0f * y0, 2.0f * y1, 2.0f * y2,
                                      fmaf(y2, y2, fmaf(y1, y1, y0 * y0)));
    }

    const int xbase = xchunk * XCHUNK + threadIdx.x * XPT;
    const float4* xp4 = (const float4*)(x + ((size_t)b * NPTS + xbase) * 3);
    const float4 a0 = xp4[0], a1 = xp4[1], a2 = xp4[2];
    const float4 a3 = xp4[3], a4 = xp4[4], a5 = xp4[5];
    const float xa[XPT][3] = {
        {a0.x, a0.y, a0.z}, {a0.w, a1.x, a1.y},
        {a1.z, a1.w, a2.x}, {a2.y, a2.z, a2.w},
        {a3.x, a3.y, a3.z}, {a3.w, a4.x, a4.y},
        {a4.z, a4.w, a5.x}, {a5.y, a5.z, a5.w}};

    float x2s[XPT];
    #pragma unroll
    for (int i = 0; i < XPT; ++i)
        x2s[i] = fmaf(xa[i][2], xa[i][2],
                 fmaf(xa[i][1], xa[i][1], xa[i][0] * xa[i][0]));

    __syncthreads();

    float m[XPT];
    #pragma unroll
    for (int i = 0; i < XPT; ++i) m[i] = 3.4e38f;

    #pragma unroll 2
    for (int j = 0; j < YTILE; j += 2) {
        const float4 Y0 = sy[j];
        const float4 Y1 = sy[j + 1];
        #pragma unroll
        for (int i = 0; i < XPT; ++i) {
            const float t0 = fmaf(-xa[i][0], Y0.x,
                             fmaf(-xa[i][1], Y0.y,
                             fmaf(-xa[i][2], Y0.z, Y0.w)));
            const float t1 = fmaf(-xa[i][0], Y1.x,
                             fmaf(-xa[i][1], Y1.y,
                             fmaf(-xa[i][2], Y1.z, Y1.w)));
            m[i] = fminf(m[i], fminf(t0, t1));
        }
    }

    unsigned int* wm = ws_min + (size_t)b * NPTS + xbase;
    #pragma unroll
    for (int i = 0; i < XPT; ++i) {
        const float d = fmaxf(x2s[i] + m[i], 0.0f);
        atomicMin(&wm[i], __float_as_uint(d));
    }
}

__global__ __launch_bounds__(BLOCK) void chamfer_sum_kernel(
    const unsigned int* __restrict__ ws_min, float* __restrict__ out)
{
    __shared__ float swsum[BLOCK / 64];
    const int total = NBATCH * NPTS;
    float s = 0.f;
    for (int i = blockIdx.x * BLOCK + threadIdx.x; i < total;
         i += gridDim.x * BLOCK)
        s += __uint_as_float(ws_min[i]);

    for (int off = 32; off > 0; off >>= 1)
        s += __shfl_down(s, off, 64);
    const int wave = threadIdx.x >> 6;
    if ((threadIdx.x & 63) == 0) swsum[wave] = s;
    __syncthreads();
    if (threadIdx.x == 0) {
        float t = 0.f;
        #pragma unroll
        for (int w = 0; w < BLOCK / 64; ++w) t += swsum[w];
        atomicAdd(out, t * (1.0f / NPTS));
    }
}

// ---------------- host ------------------------------------------------------

extern "C" void kernel_launch(void* const* d_in, const int* in_sizes, int n_in,
                              void* d_out, int out_size, void* d_ws, size_t ws_size,
                              hipStream_t stream) {
    const float* x = (const float*)d_in[0];
    const float* y = (const float*)d_in[1];
    float* out = (float*)d_out;

    const size_t need = (size_t)NBATCH * NYC * NPTS * sizeof(float);   // 8 MB

    if (ws_size >= need) {
        float* ws = (float*)d_ws;
        chamfer_part_kernel<<<NBATCH * NXC * NYC, BLOCK, 0, stream>>>(
            x, y, ws, out);
        chamfer_reduce_kernel<<<NBATCH * NPTS / BLOCK, BLOCK, 0, stream>>>(
            ws, out);
    } else {
        unsigned int* ws_min = (unsigned int*)d_ws;
        hipMemsetAsync(out, 0, sizeof(float), stream);
        hipMemsetAsync(ws_min, 0xFF, (size_t)NBATCH * NPTS * sizeof(unsigned int),
                       stream);
        chamfer_min_atomic_kernel<<<NBATCH * NXC * 16, BLOCK, 0, stream>>>(
            x, y, ws_min);
        chamfer_sum_kernel<<<64, BLOCK, 0, stream>>>(ws_min, out);
    }
}